// Round 8
// baseline (4108.598 us; speedup 1.0000x reference)
//
#include <hip/hip_runtime.h>
#include <hip/hip_bf16.h>
#include <math.h>

#define NH 32
#define NKV 8
#define HD 64
#define B_ 2
#define S_ 2048
#define E_ 2048
#define M_ 4096   // B_*S_

// ---------------- VALU tiled SGEMM: A(M,K)fp32 @ W(K,N)fp32 -> fp32 ----------------
// 64x64 tile, BK=16, block 256, 4x4 outputs/thread.
// SCATTER=0: store (M,N) row-major. SCATTER=1: store to (B,NKV,S,HD) kv layout.
template <int SCATTER>
__global__ __launch_bounds__(256) void sgemm(const float* __restrict__ A,
                                             const float* __restrict__ W,
                                             float* __restrict__ out,
                                             int M, int N, int K) {
  __shared__ float As[16][65];  // As[k][m]
  __shared__ float Bs[16][65];  // Bs[k][n]
  int m0 = blockIdx.y * 64, n0 = blockIdx.x * 64;
  int tid = threadIdx.x;
  int tx = tid & 15, ty = tid >> 4;
  float acc[4][4] = {};
  int nk = K >> 4;
  for (int kt = 0; kt < nk; kt++) {
    __syncthreads();
    for (int c = tid; c < 1024; c += 256) {
      int row = c >> 4, col = c & 15;
      As[col][row] = A[(size_t)(m0 + row) * K + kt * 16 + col];
    }
    for (int c = tid; c < 1024; c += 256) {
      int row = c >> 6, col = c & 63;
      Bs[row][col] = W[(size_t)(kt * 16 + row) * N + n0 + col];
    }
    __syncthreads();
#pragma unroll
    for (int kk = 0; kk < 16; kk++) {
      float4 a = *(const float4*)(&As[kk][ty * 4]);
      float4 b = *(const float4*)(&Bs[kk][tx * 4]);
      float av[4] = {a.x, a.y, a.z, a.w};
      float bv[4] = {b.x, b.y, b.z, b.w};
#pragma unroll
      for (int r = 0; r < 4; r++)
#pragma unroll
        for (int c = 0; c < 4; c++) acc[r][c] += av[r] * bv[c];
    }
  }
#pragma unroll
  for (int r = 0; r < 4; r++)
#pragma unroll
    for (int c = 0; c < 4; c++) {
      int row = m0 + ty * 4 + r;          // = b*S + s
      int col = n0 + tx * 4 + c;
      if (SCATTER == 0) {
        out[(size_t)row * N + col] = acc[r][c];
      } else {
        int b = row >> 11, s = row & (S_ - 1);
        int h = col >> 6, d = col & 63;
        out[((size_t)(b * NKV + h) * S_ + s) * 64 + d] = acc[r][c];
      }
    }
}

// ---------------- Q rope, in-place on fp32 q (M, 2048) = (B,S,NH,HD) ----------------
__global__ __launch_bounds__(256) void rope_q(float* __restrict__ q,
                                              const float* __restrict__ cosP,
                                              const float* __restrict__ sinP) {
  const float* cp = (cosP[0] > 0.5f) ? cosP : sinP;  // guard vs cos/sin swap
  const float* sp = (cosP[0] > 0.5f) ? sinP : cosP;
  int bs = blockIdx.x;           // b*S + s
  int s = bs & (S_ - 1);
  int tid = threadIdx.x;
  for (int p = tid; p < 1024; p += 256) {   // 32 heads x 32 pairs
    int h = p >> 5, d = p & 31;
    size_t base = (size_t)bs * E_ + h * 64 + d;
    float x1 = q[base], x2 = q[base + 32];
    float c = cp[s * 64 + d], sn = sp[s * 64 + d];
    q[base] = x1 * c - x2 * sn;
    q[base + 32] = x2 * c + x1 * sn;
  }
}

// ---------------- K rope, in-place on (B,NKV,S,HD) fp32 ----------------
__global__ __launch_bounds__(256) void rope_k(float* __restrict__ k,
                                              const float* __restrict__ cosP,
                                              const float* __restrict__ sinP) {
  const float* cp = (cosP[0] > 0.5f) ? cosP : sinP;
  const float* sp = (cosP[0] > 0.5f) ? sinP : cosP;
  int p = blockIdx.x * 256 + threadIdx.x;   // 2^20 pairs total
  int d = p & 31;
  int s = (p >> 5) & (S_ - 1);
  int h = (p >> 16) & 7;
  int b = (p >> 19) & 1;
  size_t base = ((size_t)(b * NKV + h) * S_ + s) * 64 + d;
  float x1 = k[base], x2 = k[base + 32];
  float c = cp[s * 64 + d], sn = sp[s * 64 + d];
  k[base] = x1 * c - x2 * sn;
  k[base + 32] = x2 * c + x1 * sn;
}

// ---------------- flash attention (VALU fp32, online softmax), IN-PLACE on q ----------------
// q: (B,S,NH,HD) fp32 (roped); k,v: (B,NKV,S,HD) fp32 (k roped).
// grid (32 qtiles, 64 b*h); block 256. thread: row i = tid>>2, j-quarter jq = tid&3.
// Each block reads/writes only its own q slice -> in-place safe.
__global__ __launch_bounds__(256) void attn(float* __restrict__ q,
                                            const float* __restrict__ k,
                                            const float* __restrict__ v) {
  __shared__ __align__(16) float Ks[64][68];
  __shared__ __align__(16) float Vs[64][68];
  int qt = blockIdx.x;
  int bh = blockIdx.y;
  int b = bh >> 5, h = bh & 31, g = h >> 2;
  int tid = threadIdx.x;
  int i = tid >> 2, jq = tid & 3;
  int si = qt * 64 + i;

  float qv[64];
  {
    const float4* qrow = (const float4*)(q + ((size_t)(b * S_ + si) * NH + h) * HD);
#pragma unroll
    for (int d4 = 0; d4 < 16; d4++) {
      float4 t = qrow[d4];
      qv[d4 * 4] = t.x; qv[d4 * 4 + 1] = t.y; qv[d4 * 4 + 2] = t.z; qv[d4 * 4 + 3] = t.w;
    }
  }
  float O[64];
#pragma unroll
  for (int d = 0; d < 64; d++) O[d] = 0.f;
  float mi = -INFINITY, li = 0.f;

  size_t kvbase = ((size_t)(b * NKV + g) * S_) * 64;

  for (int t = 0; t <= qt; t++) {
    __syncthreads();
    for (int c = tid; c < 1024; c += 256) {
      int row = c >> 4, d4 = c & 15;
      size_t off = kvbase + (size_t)(t * 64 + row) * 64 + d4 * 4;
      *(float4*)(&Ks[row][d4 * 4]) = *(const float4*)(k + off);
      *(float4*)(&Vs[row][d4 * 4]) = *(const float4*)(v + off);
    }
    __syncthreads();
    float sc[16];
    float mloc = -INFINITY;
#pragma unroll
    for (int jj = 0; jj < 16; jj++) {
      int j = jq + 4 * jj;
      const float4* kr = (const float4*)(&Ks[j][0]);
      float dot = 0.f;
#pragma unroll
      for (int d4 = 0; d4 < 16; d4++) {
        float4 kv = kr[d4];
        dot += qv[d4 * 4] * kv.x + qv[d4 * 4 + 1] * kv.y +
               qv[d4 * 4 + 2] * kv.z + qv[d4 * 4 + 3] * kv.w;
      }
      dot *= 0.125f;
      bool ok = (t < qt) || (j <= i);
      sc[jj] = ok ? dot : -INFINITY;
      mloc = fmaxf(mloc, sc[jj]);
    }
    mloc = fmaxf(mloc, __shfl_xor(mloc, 1));
    mloc = fmaxf(mloc, __shfl_xor(mloc, 2));
    float mnew = fmaxf(mi, mloc);
    float alpha = __expf(mi - mnew);
    float psum = 0.f;
#pragma unroll
    for (int jj = 0; jj < 16; jj++) {
      sc[jj] = __expf(sc[jj] - mnew);
      psum += sc[jj];
    }
    psum += __shfl_xor(psum, 1);
    psum += __shfl_xor(psum, 2);
    li = li * alpha + psum;
    mi = mnew;
#pragma unroll
    for (int d = 0; d < 64; d++) O[d] *= alpha;
#pragma unroll
    for (int jj = 0; jj < 16; jj++) {
      int j = jq + 4 * jj;
      float pj = sc[jj];
      const float4* vr = (const float4*)(&Vs[j][0]);
#pragma unroll
      for (int d4 = 0; d4 < 16; d4++) {
        float4 vv = vr[d4];
        O[d4 * 4] += pj * vv.x;
        O[d4 * 4 + 1] += pj * vv.y;
        O[d4 * 4 + 2] += pj * vv.z;
        O[d4 * 4 + 3] += pj * vv.w;
      }
    }
  }
#pragma unroll
  for (int d = 0; d < 64; d++) {
    O[d] += __shfl_xor(O[d], 1);
    O[d] += __shfl_xor(O[d], 2);
  }
  float inv = 1.f / li;
  float* outp = q + ((size_t)(b * S_ + si) * NH + h) * HD;
#pragma unroll
  for (int e = 0; e < 16; e++) {
    int d = jq * 16 + e;
    outp[d] = O[d] * inv;
  }
}

// ---------------- in-place row-stripe GEMM: y[r,:] = ctx[r,:] @ Wo, ctx==y ----------------
// 512 blocks x 8 rows; rows staged to LDS (fp32, 64 KB) before overwrite -> in-place safe.
__global__ __launch_bounds__(256) void rowgemm(float* __restrict__ y,
                                               const float* __restrict__ Wo) {
  __shared__ float Ls[8][2048];   // 64 KB
  int r0 = blockIdx.x * 8;
  int tid = threadIdx.x;
  for (int idx = tid; idx < 8 * 2048; idx += 256) {
    int r = idx >> 11, c = idx & 2047;
    Ls[r][c] = y[(size_t)(r0 + r) * E_ + c];
  }
  __syncthreads();
  int c0 = tid * 8;
  float acc[8][8];
#pragma unroll
  for (int r = 0; r < 8; r++)
#pragma unroll
    for (int c = 0; c < 8; c++) acc[r][c] = 0.f;
  for (int k = 0; k < 2048; k++) {
    float4 w0 = *(const float4*)(Wo + (size_t)k * E_ + c0);
    float4 w1 = *(const float4*)(Wo + (size_t)k * E_ + c0 + 4);
    float wv[8] = {w0.x, w0.y, w0.z, w0.w, w1.x, w1.y, w1.z, w1.w};
#pragma unroll
    for (int r = 0; r < 8; r++) {
      float a = Ls[r][k];
#pragma unroll
      for (int c = 0; c < 8; c++) acc[r][c] += a * wv[c];
    }
  }
#pragma unroll
  for (int r = 0; r < 8; r++)
#pragma unroll
    for (int c = 0; c < 8; c++)
      y[(size_t)(r0 + r) * E_ + c0 + c] = acc[r][c];
}

extern "C" void kernel_launch(void* const* d_in, const int* in_sizes, int n_in,
                              void* d_out, int out_size, void* d_ws, size_t ws_size,
                              hipStream_t stream) {
  // dict order (verified via size-scan equivalence, rounds 4/5): x, mask, cos, sin, Wq, Wk, Wv, Wo
  const float* x = (const float*)d_in[0];
  const float* cosT = (const float*)d_in[2];
  const float* sinT = (const float*)d_in[3];
  const float* Wq = (const float*)d_in[4];
  const float* Wk = (const float*)d_in[5];
  const float* Wv = (const float*)d_in[6];
  const float* Wo = (const float*)d_in[7];
  (void)d_ws; (void)ws_size;

  // OUTPUTS ARE FP32 (reference returns float32 tuples) — this round's single change.
  float* y = (float*)d_out;                              // (B,S,E): doubles as q/ctx scratch
  float* outk = y + (size_t)M_ * E_;                     // (B,NKV,S,HD)
  float* outv = outk + (size_t)B_ * NKV * S_ * HD;       // (B,NKV,S,HD)

  // projections: q -> y region (B,S,NH,HD); k,v -> scattered (B,NKV,S,HD)
  sgemm<0><<<dim3(32, 64), 256, 0, stream>>>(x, Wq, y, M_, 2048, 2048);
  sgemm<1><<<dim3(8, 64), 256, 0, stream>>>(x, Wk, outk, M_, 512, 2048);
  sgemm<1><<<dim3(8, 64), 256, 0, stream>>>(x, Wv, outv, M_, 512, 2048);

  rope_q<<<dim3(M_), 256, 0, stream>>>(y, cosT, sinT);
  rope_k<<<dim3(4096), 256, 0, stream>>>(outk, cosT, sinT);

  attn<<<dim3(32, 64), 256, 0, stream>>>(y, outk, outv);

  rowgemm<<<dim3(512), 256, 0, stream>>>(y, Wo);
}

// Round 9
// 869.535 us; speedup vs baseline: 4.7251x; 4.7251x over previous
//
#include <hip/hip_runtime.h>
#include <hip/hip_bf16.h>
#include <math.h>

#define NH 32
#define NKV 8
#define HD 64
#define B_ 2
#define S_ 2048
#define E_ 2048
#define M_ 4096   // B_*S_

typedef unsigned short ushort_t;
typedef __attribute__((ext_vector_type(8))) short short8;
typedef __attribute__((ext_vector_type(4))) float floatx4;

__device__ inline unsigned short f2bf(float f) {
  unsigned int u = __float_as_uint(f);
  return (unsigned short)((u + 0x7FFFu + ((u >> 16) & 1u)) >> 16);  // RNE
}
__device__ inline float bf2f(unsigned short u) {
  return __uint_as_float(((unsigned int)u) << 16);
}

// ---------------- transpose (R,C) fp32 -> (C,R) bf16 ----------------
__global__ __launch_bounds__(256) void transpose_w(const float* __restrict__ in,
                                                   ushort_t* __restrict__ out,
                                                   int R, int C) {
  __shared__ float tile[32][33];
  int c0 = blockIdx.x * 32, r0 = blockIdx.y * 32;
  int x = threadIdx.x, y0 = threadIdx.y;  // block (32,8)
  for (int i = 0; i < 4; i++) {
    int r = y0 + i * 8;
    tile[r][x] = in[(size_t)(r0 + r) * C + c0 + x];
  }
  __syncthreads();
  for (int i = 0; i < 4; i++) {
    int r = y0 + i * 8;
    out[(size_t)(c0 + r) * R + r0 + x] = f2bf(tile[x][r]);
  }
}

// ---------------- MFMA GEMM: C[M,N] = A[M,K] @ B[K,N], BT = B^T (N,K) bf16 ----------------
// 128x128 tile, BK=32, 4 waves (2x2), each wave 64x64 = 4x4 MFMA 16x16x32 bf16.
// ADYN=1: A fp32 (converted in staging); ADYN=0: A bf16.
// MODE 0: store fp32 (M,N) to outf
// MODE 1: Q-rope, store bf16 (M,N) to outb
// MODE 2: K-rope, scatter (B,NKV,S,HD): fp32 to outf AND bf16 to outb
// MODE 3: V scatter (B,NKV,S,HD): fp32 to outf AND bf16 to outb
template <int MODE, int ADYN>
__global__ __launch_bounds__(256) void gemm_bt(const void* __restrict__ Aptr,
                                               const ushort_t* __restrict__ BT,
                                               float* __restrict__ outf,
                                               ushort_t* __restrict__ outb,
                                               const float* __restrict__ cosP,
                                               const float* __restrict__ sinP,
                                               int M, int N, int K) {
  __shared__ __align__(16) ushort_t As[128][40];
  __shared__ __align__(16) ushort_t Bs[128][40];
  int tid = threadIdx.x;
  int m0 = blockIdx.y * 128, n0 = blockIdx.x * 128;
  int wave = tid >> 6, lane = tid & 63;
  int wm = (wave >> 1) * 64, wn = (wave & 1) * 64;
  int lr = lane & 15, quad = lane >> 4;
  floatx4 acc[4][4] = {};
  int nk = K >> 5;
  for (int kt = 0; kt < nk; kt++) {
    __syncthreads();
    for (int c = tid; c < 512; c += 256) {
      int row = c >> 2, c8 = c & 3;
      size_t off = (size_t)(m0 + row) * K + kt * 32 + c8 * 8;
      short8 vv;
      if (ADYN) {
        const float* ap = (const float*)Aptr + off;
        float4 a = *(const float4*)ap;
        float4 b = *(const float4*)(ap + 4);
        vv[0] = (short)f2bf(a.x); vv[1] = (short)f2bf(a.y);
        vv[2] = (short)f2bf(a.z); vv[3] = (short)f2bf(a.w);
        vv[4] = (short)f2bf(b.x); vv[5] = (short)f2bf(b.y);
        vv[6] = (short)f2bf(b.z); vv[7] = (short)f2bf(b.w);
      } else {
        vv = *(const short8*)((const ushort_t*)Aptr + off);
      }
      *(short8*)(&As[row][c8 * 8]) = vv;
    }
    for (int c = tid; c < 512; c += 256) {
      int row = c >> 2, c8 = c & 3;
      *(short8*)(&Bs[row][c8 * 8]) =
          *(const short8*)(BT + (size_t)(n0 + row) * K + kt * 32 + c8 * 8);
    }
    __syncthreads();
    short8 af[4], bfr[4];
#pragma unroll
    for (int i = 0; i < 4; i++) af[i] = *(const short8*)(&As[wm + i * 16 + lr][quad * 8]);
#pragma unroll
    for (int j = 0; j < 4; j++) bfr[j] = *(const short8*)(&Bs[wn + j * 16 + lr][quad * 8]);
#pragma unroll
    for (int i = 0; i < 4; i++)
#pragma unroll
      for (int j = 0; j < 4; j++)
        acc[i][j] = __builtin_amdgcn_mfma_f32_16x16x32_bf16(af[i], bfr[j], acc[i][j], 0, 0, 0);
  }
  // ---- epilogues (C: row = quad*4+r, col = lr; verified mapping) ----
  if (MODE == 0) {
#pragma unroll
    for (int i = 0; i < 4; i++)
#pragma unroll
      for (int j = 0; j < 4; j++) {
        int row = m0 + wm + i * 16 + quad * 4;
        int col = n0 + wn + j * 16 + lr;
#pragma unroll
        for (int r = 0; r < 4; r++)
          outf[(size_t)(row + r) * N + col] = acc[i][j][r];
      }
  }
  if (MODE == 1 || MODE == 2) {
#pragma unroll
    for (int i = 0; i < 4; i++)
#pragma unroll
      for (int j = 0; j < 2; j++) {
        int d = j * 16 + lr;  // 0..31; pairs (d, d+32) within the 64-wide head block
#pragma unroll
        for (int r = 0; r < 4; r++) {
          int row = m0 + wm + i * 16 + quad * 4 + r;
          int s = row & (S_ - 1);
          float c = cosP[s * 64 + d];
          float sn = sinP[s * 64 + d];
          float x1 = acc[i][j][r], x2 = acc[i][j + 2][r];
          float y1 = x1 * c - x2 * sn;
          float y2 = x2 * c + x1 * sn;
          if (MODE == 1) {
            size_t o = (size_t)row * N + n0 + wn + d;
            outb[o] = f2bf(y1);
            outb[o + 32] = f2bf(y2);
          } else {
            int b = row >> 11;
            int h = (n0 + wn) >> 6;
            size_t o = ((size_t)(b * NKV + h) * S_ + s) * 64 + d;
            outf[o] = y1; outf[o + 32] = y2;
            outb[o] = f2bf(y1); outb[o + 32] = f2bf(y2);
          }
        }
      }
  }
  if (MODE == 3) {
#pragma unroll
    for (int i = 0; i < 4; i++)
#pragma unroll
      for (int j = 0; j < 4; j++) {
        int col = n0 + wn + j * 16 + lr;
        int h = col >> 6, d = col & 63;
#pragma unroll
        for (int r = 0; r < 4; r++) {
          int row = m0 + wm + i * 16 + quad * 4 + r;
          int b = row >> 11, s = row & (S_ - 1);
          size_t o = ((size_t)(b * NKV + h) * S_ + s) * 64 + d;
          outf[o] = acc[i][j][r];
          outb[o] = f2bf(acc[i][j][r]);
        }
      }
  }
}

// ---------------- MFMA flash attention, IN-PLACE on qbf ----------------
// qbf: (B,S,NH,HD) bf16 roped; kbf,vbf: (B,NKV,S,HD) bf16 (k roped).
// grid (32 qtiles [reversed for LPT], 64 b*h); block 256 = 4 waves x 16 Q-rows.
__global__ __launch_bounds__(256) void attn_mfma(ushort_t* __restrict__ q,
                                                 const ushort_t* __restrict__ k,
                                                 const ushort_t* __restrict__ v) {
  __shared__ __align__(16) ushort_t Ks[64][80];      // K[key][d]
  __shared__ __align__(16) ushort_t Vt[64][80];      // V^T[d][key]
  __shared__ __align__(16) ushort_t Ps[4][16][80];   // per-wave P[qrow][key] bf16
  int qt = 31 - blockIdx.x;          // longest blocks dispatch first
  int bh = blockIdx.y;
  int b = bh >> 5, h = bh & 31, g = h >> 2;
  int tid = threadIdx.x;
  int w = tid >> 6, lane = tid & 63;
  int lr = lane & 15, quad = lane >> 4;

  // Q A-fragments (A[m=lr][k=quad*8+j]), k-chunks 0..31 / 32..63
  short8 aq[2];
  {
    size_t qb = ((size_t)(b * S_ + qt * 64 + w * 16 + lr) * NH + h) * HD;
    aq[0] = *(const short8*)(q + qb + quad * 8);
    aq[1] = *(const short8*)(q + qb + 32 + quad * 8);
  }
  floatx4 od[4] = {};
  float mi[4] = {-INFINITY, -INFINITY, -INFINITY, -INFINITY};
  float li[4] = {0.f, 0.f, 0.f, 0.f};
  size_t kvbase = ((size_t)(b * NKV + g) * S_) * HD;

  for (int t = 0; t <= qt; t++) {
    __syncthreads();
    // stage K (row-major) and V (transposed)
    for (int c = tid; c < 512; c += 256) {
      int key = c >> 3, seg = c & 7;
      size_t off = kvbase + (size_t)(t * 64 + key) * HD + seg * 8;
      *(short8*)(&Ks[key][seg * 8]) = *(const short8*)(k + off);
      short8 v8 = *(const short8*)(v + off);
#pragma unroll
      for (int e = 0; e < 8; e++) Vt[seg * 8 + e][key] = (ushort_t)v8[e];
    }
    __syncthreads();
    // QK^T: 4 key-16-tiles (B-operand from Ks, same pattern as gemm_bt)
    floatx4 sc[4];
#pragma unroll
    for (int kn = 0; kn < 4; kn++) {
      short8 b0 = *(const short8*)(&Ks[kn * 16 + lr][quad * 8]);
      short8 b1 = *(const short8*)(&Ks[kn * 16 + lr][32 + quad * 8]);
      floatx4 a = {};
      a = __builtin_amdgcn_mfma_f32_16x16x32_bf16(aq[0], b0, a, 0, 0, 0);
      a = __builtin_amdgcn_mfma_f32_16x16x32_bf16(aq[1], b1, a, 0, 0, 0);
      sc[kn] = a;
    }
    bool diag = (t == qt);
#pragma unroll
    for (int r = 0; r < 4; r++) {
      float s0 = sc[0][r] * 0.125f, s1 = sc[1][r] * 0.125f;
      float s2 = sc[2][r] * 0.125f, s3 = sc[3][r] * 0.125f;
      if (diag) {
        int qg = qt * 64 + w * 16 + quad * 4 + r;
        int kg = t * 64 + lr;
        if (kg > qg) s0 = -INFINITY;
        if (kg + 16 > qg) s1 = -INFINITY;
        if (kg + 32 > qg) s2 = -INFINITY;
        if (kg + 48 > qg) s3 = -INFINITY;
      }
      float mrow = fmaxf(fmaxf(s0, s1), fmaxf(s2, s3));
      mrow = fmaxf(mrow, __shfl_xor(mrow, 1));
      mrow = fmaxf(mrow, __shfl_xor(mrow, 2));
      mrow = fmaxf(mrow, __shfl_xor(mrow, 4));
      mrow = fmaxf(mrow, __shfl_xor(mrow, 8));
      float mn = fmaxf(mi[r], mrow);
      float al = __expf(mi[r] - mn);
      float p0 = __expf(s0 - mn), p1 = __expf(s1 - mn);
      float p2 = __expf(s2 - mn), p3 = __expf(s3 - mn);
      float ps = p0 + p1 + p2 + p3;
      ps += __shfl_xor(ps, 1);
      ps += __shfl_xor(ps, 2);
      ps += __shfl_xor(ps, 4);
      ps += __shfl_xor(ps, 8);
      li[r] = li[r] * al + ps;
      mi[r] = mn;
      od[0][r] *= al; od[1][r] *= al; od[2][r] *= al; od[3][r] *= al;
      int prow = quad * 4 + r;
      Ps[w][prow][lr] = f2bf(p0);
      Ps[w][prow][16 + lr] = f2bf(p1);
      Ps[w][prow][32 + lr] = f2bf(p2);
      Ps[w][prow][48 + lr] = f2bf(p3);
    }
    __syncthreads();   // cross-lane LDS visibility for Ps (and keeps Vt stable)
    // PV: A = P (from Ps), B = V^T (from Vt)
    short8 pa0 = *(const short8*)(&Ps[w][lr][quad * 8]);
    short8 pa1 = *(const short8*)(&Ps[w][lr][32 + quad * 8]);
#pragma unroll
    for (int dn = 0; dn < 4; dn++) {
      short8 v0 = *(const short8*)(&Vt[dn * 16 + lr][quad * 8]);
      short8 v1 = *(const short8*)(&Vt[dn * 16 + lr][32 + quad * 8]);
      od[dn] = __builtin_amdgcn_mfma_f32_16x16x32_bf16(pa0, v0, od[dn], 0, 0, 0);
      od[dn] = __builtin_amdgcn_mfma_f32_16x16x32_bf16(pa1, v1, od[dn], 0, 0, 0);
    }
  }
  float inv[4];
#pragma unroll
  for (int r = 0; r < 4; r++) inv[r] = 1.f / li[r];
#pragma unroll
  for (int dn = 0; dn < 4; dn++)
#pragma unroll
    for (int r = 0; r < 4; r++) {
      int row = qt * 64 + w * 16 + quad * 4 + r;
      size_t o = ((size_t)(b * S_ + row) * NH + h) * HD + dn * 16 + lr;
      q[o] = f2bf(od[dn][r] * inv[r]);
    }
}

extern "C" void kernel_launch(void* const* d_in, const int* in_sizes, int n_in,
                              void* d_out, int out_size, void* d_ws, size_t ws_size,
                              hipStream_t stream) {
  const float* x = (const float*)d_in[0];
  const float* cosT = (const float*)d_in[2];
  const float* sinT = (const float*)d_in[3];
  const float* Wq = (const float*)d_in[4];
  const float* Wk = (const float*)d_in[5];
  const float* Wv = (const float*)d_in[6];
  const float* Wo = (const float*)d_in[7];

  char* ws = (char*)d_ws;
  ushort_t* WqT = (ushort_t*)(ws);               //  8 MB (2048,2048)
  ushort_t* WkT = (ushort_t*)(ws + 8388608);     //  2 MB (512,2048)
  ushort_t* WvT = (ushort_t*)(ws + 10485760);    //  2 MB
  ushort_t* WoT = (ushort_t*)(ws + 12582912);    //  8 MB
  ushort_t* qbf = (ushort_t*)(ws + 20971520);    // 16 MB (B,S,NH,HD) bf16; ctx in-place
  ushort_t* kbf = (ushort_t*)(ws + 37748736);    //  4 MB (B,NKV,S,HD)
  ushort_t* vbf = (ushort_t*)(ws + 41943040);    //  4 MB -> 44 MB total

  float* y = (float*)d_out;                            // (B,S,E) fp32
  float* outk = y + (size_t)M_ * E_;                   // (B,NKV,S,HD) fp32
  float* outv = outk + (size_t)B_ * NKV * S_ * HD;

  transpose_w<<<dim3(64, 64), dim3(32, 8), 0, stream>>>(Wq, WqT, 2048, 2048);
  transpose_w<<<dim3(16, 64), dim3(32, 8), 0, stream>>>(Wk, WkT, 2048, 512);
  transpose_w<<<dim3(16, 64), dim3(32, 8), 0, stream>>>(Wv, WvT, 2048, 512);
  transpose_w<<<dim3(64, 64), dim3(32, 8), 0, stream>>>(Wo, WoT, 2048, 2048);

  // Q: rope fused -> qbf bf16. K: rope fused -> outk fp32 + kbf. V: -> outv fp32 + vbf.
  gemm_bt<1, 1><<<dim3(16, 32), 256, 0, stream>>>(x, WqT, nullptr, qbf, cosT, sinT,
                                                  M_, 2048, 2048);
  gemm_bt<2, 1><<<dim3(4, 32), 256, 0, stream>>>(x, WkT, outk, kbf, cosT, sinT,
                                                 M_, 512, 2048);
  gemm_bt<3, 1><<<dim3(4, 32), 256, 0, stream>>>(x, WvT, outv, vbf, cosT, sinT,
                                                 M_, 512, 2048);

  attn_mfma<<<dim3(32, 64), 256, 0, stream>>>(qbf, kbf, vbf);

  // O-projection: A = ctx (bf16, in qbf), out y fp32
  gemm_bt<0, 0><<<dim3(16, 32), 256, 0, stream>>>(qbf, WoT, y, nullptr, cosT, sinT,
                                                  M_, 2048, 2048);
}

// Round 10
// 454.121 us; speedup vs baseline: 9.0474x; 1.9148x over previous
//
#include <hip/hip_runtime.h>
#include <hip/hip_bf16.h>
#include <math.h>

#define NH 32
#define NKV 8
#define HD 64
#define B_ 2
#define S_ 2048
#define E_ 2048
#define M_ 4096   // B_*S_

typedef unsigned short ushort_t;
typedef __attribute__((ext_vector_type(8))) short short8;
typedef __attribute__((ext_vector_type(4))) short short4v;
typedef __attribute__((ext_vector_type(4))) float floatx4;

__device__ inline unsigned short f2bf(float f) {
  unsigned int u = __float_as_uint(f);
  return (unsigned short)((u + 0x7FFFu + ((u >> 16) & 1u)) >> 16);  // RNE
}

// async global->LDS, 16B per lane; lds base must be wave-uniform (HW adds lane*16)
__device__ inline void ld_lds16(const void* g, void* l) {
  __builtin_amdgcn_global_load_lds((__attribute__((address_space(1))) void*)g,
                                   (__attribute__((address_space(3))) void*)l, 16, 0, 0);
}

// ---------------- x fp32 -> bf16 ----------------
__global__ __launch_bounds__(256) void cast_x(const float* __restrict__ x,
                                              ushort_t* __restrict__ xb) {
  size_t i = ((size_t)blockIdx.x * 256 + threadIdx.x) * 8;
  float4 a = *(const float4*)(x + i);
  float4 b = *(const float4*)(x + i + 4);
  short8 o;
  o[0] = (short)f2bf(a.x); o[1] = (short)f2bf(a.y);
  o[2] = (short)f2bf(a.z); o[3] = (short)f2bf(a.w);
  o[4] = (short)f2bf(b.x); o[5] = (short)f2bf(b.y);
  o[6] = (short)f2bf(b.z); o[7] = (short)f2bf(b.w);
  *(short8*)(xb + i) = o;
}

// ---------------- transpose (R,C) fp32 -> (C,R) bf16 ----------------
__global__ __launch_bounds__(256) void transpose_w(const float* __restrict__ in,
                                                   ushort_t* __restrict__ out,
                                                   int R, int C) {
  __shared__ float tile[32][33];
  int c0 = blockIdx.x * 32, r0 = blockIdx.y * 32;
  int x = threadIdx.x, y0 = threadIdx.y;  // block (32,8)
  for (int i = 0; i < 4; i++) {
    int r = y0 + i * 8;
    tile[r][x] = in[(size_t)(r0 + r) * C + c0 + x];
  }
  __syncthreads();
  for (int i = 0; i < 4; i++) {
    int r = y0 + i * 8;
    out[(size_t)(c0 + r) * R + r0 + x] = f2bf(tile[x][r]);
  }
}

// ---------------- outv (B,NKV,S,HD) fp32 -> vt (B,NKV,HD,S) bf16 ----------------
__global__ __launch_bounds__(256) void transpose_v(const float* __restrict__ outv,
                                                   ushort_t* __restrict__ vt) {
  __shared__ float t64[64][65];
  int bg = blockIdx.y;        // 0..15
  int s0 = blockIdx.x * 64;   // 32 s-tiles
  int tid = threadIdx.x;
  size_t ibase = (size_t)bg * S_ * HD + (size_t)s0 * HD;
  for (int i = tid; i < 1024; i += 256) {
    int sr = i >> 4, dc = (i & 15) * 4;
    float4 v = *(const float4*)(outv + ibase + (size_t)sr * HD + dc);
    t64[sr][dc] = v.x; t64[sr][dc + 1] = v.y; t64[sr][dc + 2] = v.z; t64[sr][dc + 3] = v.w;
  }
  __syncthreads();
  size_t obase = (size_t)bg * HD * S_ + s0;
  for (int i = tid; i < 512; i += 256) {
    int d = i >> 3, ss = (i & 7) * 8;
    short8 o;
#pragma unroll
    for (int e = 0; e < 8; e++) o[e] = (short)f2bf(t64[ss + e][d]);
    *(short8*)(vt + obase + (size_t)d * S_ + ss) = o;
  }
}

// ---------------- fused QKV GEMM: xb(M,2048)bf16 @ WT^T, N=3072 ----------------
// 128x128 tile, BK=32, global_load_lds staging, unpadded LDS [128][32].
// n0<2048: Q+rope -> qbf. 2048..2559: K+rope -> outk fp32 + kbf. else: V -> outv fp32.
__global__ __launch_bounds__(256) void gemm_qkv(const ushort_t* __restrict__ xb,
                                                const ushort_t* __restrict__ WT,
                                                ushort_t* __restrict__ qbf,
                                                float* __restrict__ outk,
                                                ushort_t* __restrict__ kbf,
                                                float* __restrict__ outv,
                                                const float* __restrict__ cosP,
                                                const float* __restrict__ sinP) {
  __shared__ __align__(16) ushort_t As[128][32];
  __shared__ __align__(16) ushort_t Bs[128][32];
  const int K = 2048;
  int tid = threadIdx.x;
  int m0 = blockIdx.y * 128, n0 = blockIdx.x * 128;
  int w = tid >> 6, lane = tid & 63;
  int wm = (w >> 1) * 64, wn = (w & 1) * 64;
  int lr = lane & 15, quad = lane >> 4;
  int srow = lane >> 2, soff = (lane & 3) * 16;  // staging: 16 rows x 64B per wave-issue
  floatx4 acc[4][4] = {};
  for (int kt = 0; kt < 64; kt++) {
    __syncthreads();
#pragma unroll
    for (int j = 0; j < 2; j++) {
      int r = j * 64 + w * 16;
      ld_lds16((const char*)(xb + (size_t)(m0 + r + srow) * K) + kt * 64 + soff,
               (char*)As + r * 64);
      ld_lds16((const char*)(WT + (size_t)(n0 + r + srow) * K) + kt * 64 + soff,
               (char*)Bs + r * 64);
    }
    __syncthreads();
    short8 af[4], bf[4];
#pragma unroll
    for (int i = 0; i < 4; i++) af[i] = *(const short8*)(&As[wm + i * 16 + lr][quad * 8]);
#pragma unroll
    for (int j = 0; j < 4; j++) bf[j] = *(const short8*)(&Bs[wn + j * 16 + lr][quad * 8]);
#pragma unroll
    for (int i = 0; i < 4; i++)
#pragma unroll
      for (int j = 0; j < 4; j++)
        acc[i][j] = __builtin_amdgcn_mfma_f32_16x16x32_bf16(af[i], bf[j], acc[i][j], 0, 0, 0);
  }
  // epilogues (C: row=quad*4+r, col=lr)
  if (n0 < 2048) {  // Q + rope -> qbf
#pragma unroll
    for (int i = 0; i < 4; i++)
#pragma unroll
      for (int j = 0; j < 2; j++) {
        int d = j * 16 + lr;
#pragma unroll
        for (int r = 0; r < 4; r++) {
          int row = m0 + wm + i * 16 + quad * 4 + r;
          int s = row & (S_ - 1);
          float c = cosP[s * 64 + d], sn = sinP[s * 64 + d];
          float x1 = acc[i][j][r], x2 = acc[i][j + 2][r];
          size_t o = (size_t)row * 2048 + n0 + wn + d;
          qbf[o] = f2bf(x1 * c - x2 * sn);
          qbf[o + 32] = f2bf(x2 * c + x1 * sn);
        }
      }
  } else if (n0 < 2560) {  // K + rope -> outk fp32 + kbf bf16
    int h = (n0 - 2048 + wn) >> 6;
#pragma unroll
    for (int i = 0; i < 4; i++)
#pragma unroll
      for (int j = 0; j < 2; j++) {
        int d = j * 16 + lr;
#pragma unroll
        for (int r = 0; r < 4; r++) {
          int row = m0 + wm + i * 16 + quad * 4 + r;
          int s = row & (S_ - 1), b = row >> 11;
          float c = cosP[s * 64 + d], sn = sinP[s * 64 + d];
          float x1 = acc[i][j][r], x2 = acc[i][j + 2][r];
          float y1 = x1 * c - x2 * sn, y2 = x2 * c + x1 * sn;
          size_t o = ((size_t)(b * NKV + h) * S_ + s) * 64 + d;
          outk[o] = y1; outk[o + 32] = y2;
          kbf[o] = f2bf(y1); kbf[o + 32] = f2bf(y2);
        }
      }
  } else {  // V -> outv fp32
    int cv0 = n0 - 2560 + wn;
    int h = cv0 >> 6;
#pragma unroll
    for (int i = 0; i < 4; i++)
#pragma unroll
      for (int j = 0; j < 4; j++) {
        int d = j * 16 + lr;
#pragma unroll
        for (int r = 0; r < 4; r++) {
          int row = m0 + wm + i * 16 + quad * 4 + r;
          int s = row & (S_ - 1), b = row >> 11;
          outv[((size_t)(b * NKV + h) * S_ + s) * 64 + d] = acc[i][j][r];
        }
      }
  }
}

// ---------------- O GEMM: ctx(qbf) @ WoT^T -> y fp32 ----------------
__global__ __launch_bounds__(256) void gemm_o(const ushort_t* __restrict__ ctx,
                                              const ushort_t* __restrict__ WoT,
                                              float* __restrict__ y) {
  __shared__ __align__(16) ushort_t As[128][32];
  __shared__ __align__(16) ushort_t Bs[128][32];
  const int K = 2048, N = 2048;
  int tid = threadIdx.x;
  int m0 = blockIdx.y * 128, n0 = blockIdx.x * 128;
  int w = tid >> 6, lane = tid & 63;
  int wm = (w >> 1) * 64, wn = (w & 1) * 64;
  int lr = lane & 15, quad = lane >> 4;
  int srow = lane >> 2, soff = (lane & 3) * 16;
  floatx4 acc[4][4] = {};
  for (int kt = 0; kt < 64; kt++) {
    __syncthreads();
#pragma unroll
    for (int j = 0; j < 2; j++) {
      int r = j * 64 + w * 16;
      ld_lds16((const char*)(ctx + (size_t)(m0 + r + srow) * K) + kt * 64 + soff,
               (char*)As + r * 64);
      ld_lds16((const char*)(WoT + (size_t)(n0 + r + srow) * K) + kt * 64 + soff,
               (char*)Bs + r * 64);
    }
    __syncthreads();
    short8 af[4], bf[4];
#pragma unroll
    for (int i = 0; i < 4; i++) af[i] = *(const short8*)(&As[wm + i * 16 + lr][quad * 8]);
#pragma unroll
    for (int j = 0; j < 4; j++) bf[j] = *(const short8*)(&Bs[wn + j * 16 + lr][quad * 8]);
#pragma unroll
    for (int i = 0; i < 4; i++)
#pragma unroll
      for (int j = 0; j < 4; j++)
        acc[i][j] = __builtin_amdgcn_mfma_f32_16x16x32_bf16(af[i], bf[j], acc[i][j], 0, 0, 0);
  }
#pragma unroll
  for (int i = 0; i < 4; i++)
#pragma unroll
    for (int j = 0; j < 4; j++) {
      int row = m0 + wm + i * 16 + quad * 4;
      int col = n0 + wn + j * 16 + lr;
#pragma unroll
      for (int r = 0; r < 4; r++)
        y[(size_t)(row + r) * N + col] = acc[i][j][r];
    }
}

// ---------------- MFMA flash attention v2 (transposed QK), IN-PLACE on qbf ----------------
// qbf: (B,S,NH,HD) bf16 roped; kbf: (B,NKV,S,HD) bf16 roped; vt: (B,NKV,HD,S) bf16.
// grid (32 qtiles reversed, 64 b*h); block 256 = 4 waves x 16 qrows.
// QK^T computed transposed: C[key][qrow] -> per-lane softmax state (qrow = lr).
__global__ __launch_bounds__(256) void attn2(ushort_t* __restrict__ q,
                                             const ushort_t* __restrict__ k,
                                             const ushort_t* __restrict__ vt) {
  __shared__ __align__(16) ushort_t Ks[64][72];     // K[key][d], 9-group rows
  __shared__ __align__(16) ushort_t Vt[64][72];     // V^T[d][key]
  __shared__ __align__(16) ushort_t Ps[4][16][72];  // per-wave P[qrow][key]
  int qt = 31 - blockIdx.x;  // longest first
  int bh = blockIdx.y;
  int b = bh >> 5, h = bh & 31, g = h >> 2;
  int tid = threadIdx.x;
  int w = tid >> 6, lane = tid & 63;
  int lr = lane & 15, quad = lane >> 4;

  int qg = qt * 64 + w * 16 + lr;  // this lane's query row
  short8 aq0, aq1;                 // Q B-frag (Q^T operand)
  {
    const ushort_t* qp = q + ((size_t)(b * S_ + qg) * NH + h) * HD;
    aq0 = *(const short8*)(qp + quad * 8);
    aq1 = *(const short8*)(qp + 32 + quad * 8);
  }
  floatx4 od[4] = {};  // O^T[d=dn*16+quad*4+r][qrow=lr]
  float mi = -INFINITY, li = 0.f;
  size_t kbase = (size_t)(b * NKV + g) * S_ * HD;  // (B,NKV,S,HD)
  size_t vbase = (size_t)(b * NKV + g) * HD * S_;  // (B,NKV,HD,S)

  for (int t = 0; t <= qt; t++) {
    __syncthreads();
    for (int i = tid; i < 512; i += 256) {
      int row = i >> 3, seg = i & 7;
      *(short8*)(&Ks[row][seg * 8]) =
          *(const short8*)(k + kbase + (size_t)(t * 64 + row) * HD + seg * 8);
      *(short8*)(&Vt[row][seg * 8]) =
          *(const short8*)(vt + vbase + (size_t)row * S_ + t * 64 + seg * 8);
    }
    __syncthreads();
    // S^T = K · Q^T : 4 key-tiles
    floatx4 sc[4];
#pragma unroll
    for (int kn = 0; kn < 4; kn++) {
      short8 a0 = *(const short8*)(&Ks[kn * 16 + lr][quad * 8]);
      short8 a1 = *(const short8*)(&Ks[kn * 16 + lr][32 + quad * 8]);
      floatx4 c = {};
      c = __builtin_amdgcn_mfma_f32_16x16x32_bf16(a0, aq0, c, 0, 0, 0);
      c = __builtin_amdgcn_mfma_f32_16x16x32_bf16(a1, aq1, c, 0, 0, 0);
      sc[kn] = c;
    }
    // per-lane online softmax over 16 in-lane scores + cross-quad reduce
    float pv[16];
    float mx = -INFINITY;
    bool diag = (t == qt);
#pragma unroll
    for (int kn = 0; kn < 4; kn++)
#pragma unroll
      for (int r = 0; r < 4; r++) {
        float s = sc[kn][r] * 0.125f;
        int kg = t * 64 + kn * 16 + quad * 4 + r;
        if (diag && kg > qg) s = -INFINITY;
        pv[kn * 4 + r] = s;
        mx = fmaxf(mx, s);
      }
    mx = fmaxf(mx, __shfl_xor(mx, 16));
    mx = fmaxf(mx, __shfl_xor(mx, 32));
    float mn = fmaxf(mi, mx);
    float al = __expf(mi - mn);
    float ps = 0.f;
#pragma unroll
    for (int e = 0; e < 16; e++) {
      pv[e] = __expf(pv[e] - mn);
      ps += pv[e];
    }
    ps += __shfl_xor(ps, 16);
    ps += __shfl_xor(ps, 32);
    li = li * al + ps;
    mi = mn;
#pragma unroll
    for (int dn = 0; dn < 4; dn++) {
      od[dn][0] *= al; od[dn][1] *= al; od[dn][2] *= al; od[dn][3] *= al;
    }
    // store P: row qrow=lr, keys kn*16+quad*4+0..3 -> b64 vector stores
#pragma unroll
    for (int kn = 0; kn < 4; kn++) {
      short4v u;
      u[0] = (short)f2bf(pv[kn * 4 + 0]); u[1] = (short)f2bf(pv[kn * 4 + 1]);
      u[2] = (short)f2bf(pv[kn * 4 + 2]); u[3] = (short)f2bf(pv[kn * 4 + 3]);
      *(short4v*)(&Ps[w][lr][kn * 16 + quad * 4]) = u;
    }
    // O^T += V^T · P^T  (same-wave LDS; compiler inserts lgkm waits)
    short8 pb0 = *(const short8*)(&Ps[w][lr][quad * 8]);
    short8 pb1 = *(const short8*)(&Ps[w][lr][32 + quad * 8]);
#pragma unroll
    for (int dn = 0; dn < 4; dn++) {
      short8 va = *(const short8*)(&Vt[dn * 16 + lr][quad * 8]);
      short8 vb = *(const short8*)(&Vt[dn * 16 + lr][32 + quad * 8]);
      od[dn] = __builtin_amdgcn_mfma_f32_16x16x32_bf16(va, pb0, od[dn], 0, 0, 0);
      od[dn] = __builtin_amdgcn_mfma_f32_16x16x32_bf16(vb, pb1, od[dn], 0, 0, 0);
    }
  }
  float inv = 1.f / li;
  ushort_t* outp = q + ((size_t)(b * S_ + qg) * NH + h) * HD;
#pragma unroll
  for (int dn = 0; dn < 4; dn++) {
    short4v u;
    u[0] = (short)f2bf(od[dn][0] * inv); u[1] = (short)f2bf(od[dn][1] * inv);
    u[2] = (short)f2bf(od[dn][2] * inv); u[3] = (short)f2bf(od[dn][3] * inv);
    *(short4v*)(outp + dn * 16 + quad * 4) = u;
  }
}

extern "C" void kernel_launch(void* const* d_in, const int* in_sizes, int n_in,
                              void* d_out, int out_size, void* d_ws, size_t ws_size,
                              hipStream_t stream) {
  const float* x = (const float*)d_in[0];
  const float* cosT = (const float*)d_in[2];
  const float* sinT = (const float*)d_in[3];
  const float* Wq = (const float*)d_in[4];
  const float* Wk = (const float*)d_in[5];
  const float* Wv = (const float*)d_in[6];
  const float* Wo = (const float*)d_in[7];

  char* ws = (char*)d_ws;
  ushort_t* WT = (ushort_t*)(ws);                 // 12 MB (3072, 2048): Wq^T | Wk^T | Wv^T
  ushort_t* WoT = (ushort_t*)(ws + 12582912);     //  8 MB (2048, 2048)
  ushort_t* xb = (ushort_t*)(ws + 20971520);      // 16 MB (M, 2048) bf16
  ushort_t* qbf = (ushort_t*)(ws + 37748736);     // 16 MB (B,S,NH,HD); ctx in-place
  ushort_t* kbf = (ushort_t*)(ws + 54525952);     //  4 MB (B,NKV,S,HD)
  ushort_t* vt = (ushort_t*)(ws + 58720256);      //  4 MB (B,NKV,HD,S) -> 60 MB total

  float* y = (float*)d_out;                            // (B,S,E) fp32
  float* outk = y + (size_t)M_ * E_;                   // (B,NKV,S,HD) fp32
  float* outv = outk + (size_t)B_ * NKV * S_ * HD;     // (B,NKV,S,HD) fp32

  cast_x<<<dim3(4096), 256, 0, stream>>>(x, xb);
  transpose_w<<<dim3(64, 64), dim3(32, 8), 0, stream>>>(Wq, WT, 2048, 2048);
  transpose_w<<<dim3(16, 64), dim3(32, 8), 0, stream>>>(Wk, WT + 2048 * 2048, 2048, 512);
  transpose_w<<<dim3(16, 64), dim3(32, 8), 0, stream>>>(Wv, WT + 2560 * 2048, 2048, 512);
  transpose_w<<<dim3(64, 64), dim3(32, 8), 0, stream>>>(Wo, WoT, 2048, 2048);

  gemm_qkv<<<dim3(24, 32), 256, 0, stream>>>(xb, WT, qbf, outk, kbf, outv, cosT, sinT);
  transpose_v<<<dim3(32, 16), 256, 0, stream>>>(outv, vt);

  attn2<<<dim3(32, 64), 256, 0, stream>>>(qbf, kbf, vt);

  gemm_o<<<dim3(16, 32), 256, 0, stream>>>(qbf, WoT, y);
}